// Round 1
// 696.218 us; speedup vs baseline: 1.2209x; 1.2209x over previous
//
#include <hip/hip_runtime.h>
#include <hip/hip_bf16.h>
#include <math.h>

// Problem dims
constexpr int NB    = 64;
constexpr int NTX   = 1024;
constexpr int NAD   = 1024;   // ADIM
constexpr int NU    = 1024;   // UNITS
constexpr int NE    = 512;    // EDIM
constexpr int NV    = 32000;  // VOCAB
constexpr int KX    = NAD + NE;      // 1536 (rows of Wx)
constexpr int KTOT  = KX + NU;       // 2560 (concat K for z-GEMM)
constexpr int G4    = 4 * NU;        // 4096
constexpr int NTC   = 16;            // t-chunks for context reduce

// Workspace layout (floats)
constexpr size_t OFF_AT  = 0;                          // At[k][b]  : KTOT*NB   = 163840
constexpr size_t OFF_Z   = OFF_AT + (size_t)KTOT * NB; // zacc[b][u]: NB*G4     = 262144
constexpr size_t OFF_HT  = OFF_Z + (size_t)NB * G4;    // Ht[k][b]  : NU*NB     = 65536
constexpr size_t OFF_SCR = OFF_HT + (size_t)NU * NB;   // union{ part[16][B][AD]=1048576 , logits[B][V]=2048000 }

// Out layout (fp32 elements), reference return order:
// (y_pred[B,V], context[B,1,A], alpha[B,Tx], h_new[B,U], c_new[B,U])
constexpr size_t OUT_Y     = 0;
constexpr size_t OUT_CTX   = (size_t)NB * NV;           // 2048000
constexpr size_t OUT_ALPHA = OUT_CTX + (size_t)NB * NAD;
constexpr size_t OUT_H     = OUT_ALPHA + (size_t)NB * NTX;
constexpr size_t OUT_C     = OUT_H + (size_t)NB * NU;

__device__ __forceinline__ float sigf(float x) { return 1.0f / (1.0f + __expf(-x)); }

// ---- 1) z := bl (bias init; also serves as the atomic accumulator init) ----
__global__ __launch_bounds__(256) void k_zinit(const float* __restrict__ bl,
                                               float* __restrict__ zacc) {
    int i = blockIdx.x * 256 + threadIdx.x;      // grid 1024*256 == NB*G4 exactly
    zacc[i] = bl[i & (G4 - 1)];
}

// ---- 2) context partials: part[tc][b][d] = sum_{t in chunk} a[b][t][d] ------
// unroll 8: 8 independent 16B/lane loads in flight -> HBM roofline
__global__ __launch_bounds__(256) void k_ctx(const float* __restrict__ a,
                                             float* __restrict__ part) {
    int tc = blockIdx.x, b = blockIdx.y, tid = threadIdx.x;
    float4 acc = make_float4(0.f, 0.f, 0.f, 0.f);
    int t0 = tc * (NTX / NTC);
    #pragma unroll 8
    for (int tt = 0; tt < NTX / NTC; ++tt) {
        const float4* row = (const float4*)(a + ((size_t)b * NTX + t0 + tt) * NAD);
        float4 v = row[tid];                     // 4 f32, coalesced 16B/lane
        acc.x += v.x; acc.y += v.y; acc.z += v.z; acc.w += v.w;
    }
    float4* p4 = (float4*)(part + ((size_t)tc * NB + b) * NAD + tid * 4);
    *p4 = acc;
}

// ---- 3) finalize context; build At[k][b] = [ctx | emb | h]; alpha := 1 ------
__global__ __launch_bounds__(128) void k_ctx_fin(const float* __restrict__ part,
                                                 const int* __restrict__ X,
                                                 const float* __restrict__ emb,
                                                 const float* __restrict__ h,
                                                 float* __restrict__ At,
                                                 float* __restrict__ out_ctx,
                                                 float* __restrict__ out_alpha) {
    int b = blockIdx.x, tid = threadIdx.x;
    int d0 = tid * 8;
    float s[8] = {};
    for (int tc = 0; tc < NTC; ++tc) {
        const float* p = part + ((size_t)tc * NB + b) * NAD + d0;
        #pragma unroll
        for (int i = 0; i < 8; ++i) s[i] += p[i];
    }
    #pragma unroll
    for (int i = 0; i < 8; ++i) {
        At[(size_t)(d0 + i) * NB + b] = s[i];
        out_ctx[(size_t)b * NAD + d0 + i] = s[i];
    }
    int row = X[b];
    for (int j = tid; j < NE; j += 128)
        At[(size_t)(NAD + j) * NB + b] = emb[(size_t)row * NE + j];
    for (int j = tid; j < NU; j += 128)
        At[(size_t)(KX + j) * NB + b] = h[(size_t)b * NU + j];
    for (int j = tid; j < NTX; j += 128)
        out_alpha[(size_t)b * NTX + j] = 1.0f;
}

// ---- 4) z-GEMM: zacc[b][u] += sum_k At[k][b] * W[k][u], K split 8-way -------
// 8-deep w-prefetch: the W column loads stride 16KB (every load is a fresh
// line) -> keep 8 independent loads in flight per wave to cover the latency.
__global__ __launch_bounds__(256) void k_zgemm(const float* __restrict__ At,
                                               const float* __restrict__ Wx,
                                               const float* __restrict__ Wh,
                                               float* __restrict__ zacc) {
    int tid = threadIdx.x;
    int u = blockIdx.x * 64 + (tid & 63);
    int b0 = __builtin_amdgcn_readfirstlane(tid >> 6) * 16;  // wave-uniform
    int k0 = blockIdx.y * (KTOT / 8);                        // 320 (mult of 8)
    float acc[16] = {};
    for (int kk0 = 0; kk0 < KTOT / 8; kk0 += 8) {
        float w[8];
        #pragma unroll
        for (int j = 0; j < 8; ++j) {
            int k = k0 + kk0 + j;
            w[j] = (k < KX) ? Wx[(size_t)k * G4 + u]
                            : Wh[(size_t)(k - KX) * G4 + u];
        }
        #pragma unroll
        for (int j = 0; j < 8; ++j) {
            const float* ap = At + (size_t)(k0 + kk0 + j) * NB + b0;  // uniform
            #pragma unroll
            for (int i = 0; i < 16; ++i) acc[i] = fmaf(ap[i], w[j], acc[i]);
        }
    }
    #pragma unroll
    for (int i = 0; i < 16; ++i)
        atomicAdd(&zacc[(size_t)(b0 + i) * G4 + u], acc[i]);
}

// ---- 5) gates: c_new, h_new; Ht[k][b] for the vocab GEMM --------------------
__global__ __launch_bounds__(256) void k_gates(const float* __restrict__ zacc,
                                               const float* __restrict__ c,
                                               float* __restrict__ out_h,
                                               float* __restrict__ out_c,
                                               float* __restrict__ Ht) {
    int b = blockIdx.x, tid = threadIdx.x;
    const float* z = zacc + (size_t)b * G4;
    #pragma unroll
    for (int l = 0; l < 4; ++l) {
        int j = tid * 4 + l;
        float zi = z[j], zf = z[NU + j], zg = z[2 * NU + j], zo = z[3 * NU + j];
        float cf = c[(size_t)b * NU + j];
        float cn = sigf(zf) * cf + sigf(zi) * tanhf(zg);
        float hn = sigf(zo) * tanhf(cn);
        out_c[(size_t)b * NU + j] = cn;
        out_h[(size_t)b * NU + j] = hn;
        Ht[(size_t)j * NB + b] = hn;
    }
}

// ---- 6) vocab GEMM: logits[b][u] = sum_k Ht[k][b]*Wv[k][u] + bv[u] ----------
// Was latency-bound (VALUBusy 12.7%, 305 GB/s): the Wv column load strides
// 128KB so every k-iter waits a full miss with only unroll-2 MLP.
// Fix: prefetch 8 w-values (8 independent coalesced 256B wave-loads in
// flight), then the 128 FMAs. Ht stays wave-uniform (scalar-cached, hot).
__global__ __launch_bounds__(256) void k_vgemm(const float* __restrict__ Ht,
                                               const float* __restrict__ Wv,
                                               const float* __restrict__ bv,
                                               float* __restrict__ logits) {
    int tid = threadIdx.x;
    int u = blockIdx.x * 64 + (tid & 63);
    int b0 = __builtin_amdgcn_readfirstlane(tid >> 6) * 16;
    float acc[16] = {};
    const float* wcol = Wv + u;
    for (int k0 = 0; k0 < NU; k0 += 8) {
        float w[8];
        #pragma unroll
        for (int j = 0; j < 8; ++j)
            w[j] = wcol[(size_t)(k0 + j) * NV];
        #pragma unroll
        for (int j = 0; j < 8; ++j) {
            const float* ap = Ht + (size_t)(k0 + j) * NB + b0;   // wave-uniform
            #pragma unroll
            for (int i = 0; i < 16; ++i) acc[i] = fmaf(ap[i], w[j], acc[i]);
        }
    }
    float bvu = bv[u];
    #pragma unroll
    for (int i = 0; i < 16; ++i)
        logits[(size_t)(b0 + i) * NV + u] = acc[i] + bvu;
}

// ---- 7) row softmax over 32000 ---------------------------------------------
__global__ __launch_bounds__(256) void k_softmax(const float* __restrict__ logits,
                                                 float* __restrict__ y) {
    __shared__ float red[256];
    int b = blockIdx.x, tid = threadIdx.x;
    const float* row = logits + (size_t)b * NV;
    float m = -1e30f;
    for (int i = tid; i < NV; i += 256) m = fmaxf(m, row[i]);
    red[tid] = m; __syncthreads();
    for (int s = 128; s > 0; s >>= 1) {
        if (tid < s) red[tid] = fmaxf(red[tid], red[tid + s]);
        __syncthreads();
    }
    float M = red[0]; __syncthreads();
    float ssum = 0.0f;
    for (int i = tid; i < NV; i += 256) ssum += __expf(row[i] - M);
    red[tid] = ssum; __syncthreads();
    for (int s = 128; s > 0; s >>= 1) {
        if (tid < s) red[tid] += red[tid + s];
        __syncthreads();
    }
    float inv = 1.0f / red[0];
    for (int i = tid; i < NV; i += 256)
        y[(size_t)b * NV + i] = __expf(row[i] - M) * inv;
}

extern "C" void kernel_launch(void* const* d_in, const int* in_sizes, int n_in,
                              void* d_out, int out_size, void* d_ws, size_t ws_size,
                              hipStream_t stream) {
    const int*   X   = (const int*)d_in[0];
    const float* a   = (const float*)d_in[1];
    const float* h   = (const float*)d_in[2];
    const float* c   = (const float*)d_in[3];
    const float* emb = (const float*)d_in[4];
    // d_in[5..10] = W1,b1,W2,b2,We,be — dead (softmax over size-1 axis == 1)
    const float* Wx  = (const float*)d_in[11];
    const float* Wh  = (const float*)d_in[12];
    const float* bl  = (const float*)d_in[13];
    const float* Wv  = (const float*)d_in[14];
    const float* bv  = (const float*)d_in[15];

    float* out = (float*)d_out;
    float* ws  = (float*)d_ws;
    float* At      = ws + OFF_AT;
    float* zacc    = ws + OFF_Z;
    float* Ht      = ws + OFF_HT;
    float* scratch = ws + OFF_SCR;   // part[] then (after it's dead) logits[]

    float* out_y     = out + OUT_Y;
    float* out_ctx   = out + OUT_CTX;
    float* out_alpha = out + OUT_ALPHA;
    float* out_h     = out + OUT_H;
    float* out_c     = out + OUT_C;

    hipLaunchKernelGGL(k_zinit,   dim3(1024),     dim3(256), 0, stream, bl, zacc);
    hipLaunchKernelGGL(k_ctx,     dim3(NTC, NB),  dim3(256), 0, stream, a, scratch);
    hipLaunchKernelGGL(k_ctx_fin, dim3(NB),       dim3(128), 0, stream, scratch, X, emb, h, At, out_ctx, out_alpha);
    hipLaunchKernelGGL(k_zgemm,   dim3(G4/64, 8), dim3(256), 0, stream, At, Wx, Wh, zacc);
    hipLaunchKernelGGL(k_gates,   dim3(NB),       dim3(256), 0, stream, zacc, c, out_h, out_c, Ht);
    hipLaunchKernelGGL(k_vgemm,   dim3(NV/64),    dim3(256), 0, stream, Ht, Wv, bv, scratch);
    hipLaunchKernelGGL(k_softmax, dim3(NB),       dim3(256), 0, stream, scratch, out_y);
}

// Round 2
// 686.298 us; speedup vs baseline: 1.2386x; 1.0145x over previous
//
#include <hip/hip_runtime.h>
#include <hip/hip_bf16.h>
#include <math.h>

// Problem dims
constexpr int NB    = 64;
constexpr int NTX   = 1024;
constexpr int NAD   = 1024;   // ADIM
constexpr int NU    = 1024;   // UNITS
constexpr int NE    = 512;    // EDIM
constexpr int NV    = 32000;  // VOCAB
constexpr int KX    = NAD + NE;      // 1536 (rows of Wx)
constexpr int KTOT  = KX + NU;       // 2560 (concat K for z-GEMM)
constexpr int G4    = 4 * NU;        // 4096
constexpr int NTC   = 16;            // t-chunks for context reduce
constexpr int ZKS   = 16;            // z-GEMM k-split chunks (KTOT/ZKS = 160)

// Workspace layout (floats)
constexpr size_t OFF_AT  = 0;                          // At[k][b]  : KTOT*NB   = 163840
constexpr size_t OFF_Z   = OFF_AT + (size_t)KTOT * NB; // zacc[b][u]: NB*G4     = 262144
constexpr size_t OFF_HT  = OFF_Z + (size_t)NB * G4;    // Ht[k][b]  : NU*NB     = 65536
constexpr size_t OFF_SCR = OFF_HT + (size_t)NU * NB;   // union{ part[16][B][AD] , logits[B][V] }
constexpr size_t OFF_SM  = OFF_SCR + (size_t)NB * NV;  // softmax partials: 512 floats

// Out layout (fp32 elements), reference return order:
// (y_pred[B,V], context[B,1,A], alpha[B,Tx], h_new[B,U], c_new[B,U])
constexpr size_t OUT_Y     = 0;
constexpr size_t OUT_CTX   = (size_t)NB * NV;           // 2048000
constexpr size_t OUT_ALPHA = OUT_CTX + (size_t)NB * NAD;
constexpr size_t OUT_H     = OUT_ALPHA + (size_t)NB * NTX;
constexpr size_t OUT_C     = OUT_H + (size_t)NB * NU;

__device__ __forceinline__ float sigf(float x) { return 1.0f / (1.0f + __expf(-x)); }

// ---- 1) z := bl (bias init; also serves as the atomic accumulator init) ----
__global__ __launch_bounds__(256) void k_zinit(const float* __restrict__ bl,
                                               float* __restrict__ zacc) {
    int i = blockIdx.x * 256 + threadIdx.x;      // grid 1024*256 == NB*G4 exactly
    zacc[i] = bl[i & (G4 - 1)];
}

// ---- 2) context partials: part[tc][b][d] = sum_{t in chunk} a[b][t][d] ------
__global__ __launch_bounds__(256) void k_ctx(const float* __restrict__ a,
                                             float* __restrict__ part) {
    int tc = blockIdx.x, b = blockIdx.y, tid = threadIdx.x;
    float4 acc = make_float4(0.f, 0.f, 0.f, 0.f);
    int t0 = tc * (NTX / NTC);
    #pragma unroll 8
    for (int tt = 0; tt < NTX / NTC; ++tt) {
        const float4* row = (const float4*)(a + ((size_t)b * NTX + t0 + tt) * NAD);
        float4 v = row[tid];                     // 4 f32, coalesced 16B/lane
        acc.x += v.x; acc.y += v.y; acc.z += v.z; acc.w += v.w;
    }
    float4* p4 = (float4*)(part + ((size_t)tc * NB + b) * NAD + tid * 4);
    *p4 = acc;
}

// ---- 3) finalize context; build At[k][b] = [ctx | emb | h]; alpha := 1 ------
__global__ __launch_bounds__(128) void k_ctx_fin(const float* __restrict__ part,
                                                 const int* __restrict__ X,
                                                 const float* __restrict__ emb,
                                                 const float* __restrict__ h,
                                                 float* __restrict__ At,
                                                 float* __restrict__ out_ctx,
                                                 float* __restrict__ out_alpha) {
    int b = blockIdx.x, tid = threadIdx.x;
    int d0 = tid * 8;
    float s[8] = {};
    for (int tc = 0; tc < NTC; ++tc) {
        const float* p = part + ((size_t)tc * NB + b) * NAD + d0;
        #pragma unroll
        for (int i = 0; i < 8; ++i) s[i] += p[i];
    }
    #pragma unroll
    for (int i = 0; i < 8; ++i) {
        At[(size_t)(d0 + i) * NB + b] = s[i];
        out_ctx[(size_t)b * NAD + d0 + i] = s[i];
    }
    int row = X[b];
    for (int j = tid; j < NE; j += 128)
        At[(size_t)(NAD + j) * NB + b] = emb[(size_t)row * NE + j];
    for (int j = tid; j < NU; j += 128)
        At[(size_t)(KX + j) * NB + b] = h[(size_t)b * NU + j];
    for (int j = tid; j < NTX; j += 128)
        out_alpha[(size_t)b * NTX + j] = 1.0f;
}

// ---- 4) z-GEMM: zacc[b][u] += sum_k At[k][b] * W[k][u] ---------------------
// float2 W loads + double-buffered pipeline; grid (G4/128, ZKS) = (32,16),
// 256 thr (4 waves x 16 b-rows). Chunk = 160 k = 20 groups of 8.
#define ZG_LD(buf, g)                                                          \
    _Pragma("unroll")                                                          \
    for (int j = 0; j < 8; ++j) {                                              \
        int k = kbeg + (g) * 8 + j;                                            \
        const float2* base = (k < KX) ? (Wx2 + (size_t)k * (G4 / 2))           \
                                      : (Wh2 + (size_t)(k - KX) * (G4 / 2));   \
        buf[j] = base[uq];                                                     \
    }

#define ZG_FMA(buf, g)                                                         \
    _Pragma("unroll")                                                          \
    for (int j = 0; j < 8; ++j) {                                              \
        const float* ap = At + (size_t)(kbeg + (g) * 8 + j) * NB + b0;         \
        _Pragma("unroll")                                                      \
        for (int i = 0; i < 16; ++i) {                                         \
            acc[i].x = fmaf(ap[i], buf[j].x, acc[i].x);                        \
            acc[i].y = fmaf(ap[i], buf[j].y, acc[i].y);                        \
        }                                                                      \
    }

__global__ __launch_bounds__(256) void k_zgemm(const float* __restrict__ At,
                                               const float* __restrict__ Wx,
                                               const float* __restrict__ Wh,
                                               float* __restrict__ zacc) {
    int tid = threadIdx.x;
    int lane = tid & 63;
    int b0 = __builtin_amdgcn_readfirstlane(tid >> 6) * 16;  // wave-uniform
    int uq = blockIdx.x * 64 + lane;                         // float2 index
    int kbeg = blockIdx.y * (KTOT / ZKS);                    // 160
    const float2* Wx2 = (const float2*)Wx;
    const float2* Wh2 = (const float2*)Wh;
    float2 acc[16];
    #pragma unroll
    for (int i = 0; i < 16; ++i) acc[i] = make_float2(0.f, 0.f);
    float2 bA[8], bB[8];
    constexpr int NG = (KTOT / ZKS) / 8;                     // 20 (even)
    ZG_LD(bA, 0);
    for (int g = 0; g < NG; g += 2) {
        ZG_LD(bB, g + 1);
        ZG_FMA(bA, g);
        if (g + 2 < NG) ZG_LD(bA, g + 2);
        ZG_FMA(bB, g + 1);
    }
    int u0 = uq * 2;
    #pragma unroll
    for (int i = 0; i < 16; ++i) {
        atomicAdd(&zacc[(size_t)(b0 + i) * G4 + u0],     acc[i].x);
        atomicAdd(&zacc[(size_t)(b0 + i) * G4 + u0 + 1], acc[i].y);
    }
}

// ---- 5) gates: c_new, h_new; Ht[k][b] for the vocab GEMM --------------------
__global__ __launch_bounds__(256) void k_gates(const float* __restrict__ zacc,
                                               const float* __restrict__ c,
                                               float* __restrict__ out_h,
                                               float* __restrict__ out_c,
                                               float* __restrict__ Ht) {
    int b = blockIdx.x, tid = threadIdx.x;
    const float* z = zacc + (size_t)b * G4;
    #pragma unroll
    for (int l = 0; l < 4; ++l) {
        int j = tid * 4 + l;
        float zi = z[j], zf = z[NU + j], zg = z[2 * NU + j], zo = z[3 * NU + j];
        float cf = c[(size_t)b * NU + j];
        float cn = sigf(zf) * cf + sigf(zi) * tanhf(zg);
        float hn = sigf(zo) * tanhf(cn);
        out_c[(size_t)b * NU + j] = cn;
        out_h[(size_t)b * NU + j] = hn;
        Ht[(size_t)j * NB + b] = hn;
    }
}

// ---- 6) vocab GEMM: logits[b][u] = sum_k Ht[k][b]*Wv[k][u] + bv[u] ----------
// 8 waves: (w&3) picks 16 b-rows, (w>>2) picks k-half (512 k). float2 Wv
// loads, double-buffered pipeline; LDS reduce between k-halves; non-atomic
// bias-folded store. Grid NV/128 = 250 blocks -> 2 waves/SIMD.
#define VG_LD(buf, g)                                                          \
    _Pragma("unroll")                                                          \
    for (int j = 0; j < 8; ++j)                                                \
        buf[j] = wp[(size_t)((g) * 8 + j) * (NV / 2)];

#define VG_FMA(buf, g)                                                         \
    _Pragma("unroll")                                                          \
    for (int j = 0; j < 8; ++j) {                                              \
        const float* ap = Ht + (size_t)(kbeg + (g) * 8 + j) * NB + b0;         \
        _Pragma("unroll")                                                      \
        for (int i = 0; i < 16; ++i) {                                         \
            acc[i].x = fmaf(ap[i], buf[j].x, acc[i].x);                        \
            acc[i].y = fmaf(ap[i], buf[j].y, acc[i].y);                        \
        }                                                                      \
    }

__global__ __launch_bounds__(512) void k_vgemm(const float* __restrict__ Ht,
                                               const float* __restrict__ Wv,
                                               const float* __restrict__ bv,
                                               float* __restrict__ logits) {
    __shared__ float red[4][64][33];   // +1 pad: 2-way banks only (free)
    int tid = threadIdx.x;
    int lane = tid & 63;
    int w  = __builtin_amdgcn_readfirstlane(tid >> 6);
    int bw = w & 3;
    int kc = w >> 2;                   // 0 or 1: k-half
    int b0 = bw * 16;
    int uq = blockIdx.x * 64 + lane;   // float2 column index
    int kbeg = kc * (NU / 2);          // 0 or 512
    const float2* Wv2 = (const float2*)Wv;
    const float2* wp = Wv2 + (size_t)kbeg * (NV / 2) + uq;
    float2 acc[16];
    #pragma unroll
    for (int i = 0; i < 16; ++i) acc[i] = make_float2(0.f, 0.f);
    float2 bA[8], bB[8];
    constexpr int NG = (NU / 2) / 8;   // 64 (even)
    VG_LD(bA, 0);
    for (int g = 0; g < NG; g += 2) {
        VG_LD(bB, g + 1);
        VG_FMA(bA, g);
        if (g + 2 < NG) VG_LD(bA, g + 2);
        VG_FMA(bB, g + 1);
    }
    if (kc == 1) {
        #pragma unroll
        for (int i = 0; i < 16; ++i) {
            red[bw][lane][2 * i]     = acc[i].x;
            red[bw][lane][2 * i + 1] = acc[i].y;
        }
    }
    __syncthreads();
    if (kc == 0) {
        float2 bvv = ((const float2*)bv)[uq];
        #pragma unroll
        for (int i = 0; i < 16; ++i) {
            float2 r;
            r.x = acc[i].x + red[bw][lane][2 * i]     + bvv.x;
            r.y = acc[i].y + red[bw][lane][2 * i + 1] + bvv.y;
            ((float2*)(logits + (size_t)(b0 + i) * NV))[uq] = r;
        }
    }
}

// ---- 7a) softmax partials: per (b, quarter) max & sum ----------------------
// grid (4, NB), 256 thr; each block scans 2000 float4 (8-deep batched loads).
__global__ __launch_bounds__(256) void k_smax1(const float* __restrict__ logits,
                                               float* __restrict__ smp) {
    __shared__ float lm[4], ls[4];
    int q = blockIdx.x, b = blockIdx.y, tid = threadIdx.x;
    const float4* row4 = (const float4*)(logits + (size_t)b * NV) + q * 2000;
    float4 v[8];
    #pragma unroll
    for (int j = 0; j < 8; ++j) {
        int idx = tid + 256 * j;
        v[j] = (idx < 2000) ? row4[idx]
                            : make_float4(-1e30f, -1e30f, -1e30f, -1e30f);
    }
    float m = -1e30f;
    #pragma unroll
    for (int j = 0; j < 8; ++j)
        m = fmaxf(m, fmaxf(fmaxf(v[j].x, v[j].y), fmaxf(v[j].z, v[j].w)));
    float s = 0.0f;
    #pragma unroll
    for (int j = 0; j < 8; ++j)
        s += __expf(v[j].x - m) + __expf(v[j].y - m) +
             __expf(v[j].z - m) + __expf(v[j].w - m);
    #pragma unroll
    for (int off = 32; off > 0; off >>= 1) {
        float om = __shfl_xor(m, off);
        float os = __shfl_xor(s, off);
        float M = fmaxf(m, om);
        s = s * __expf(m - M) + os * __expf(om - M);
        m = M;
    }
    int wv = tid >> 6, lane = tid & 63;
    if (lane == 0) { lm[wv] = m; ls[wv] = s; }
    __syncthreads();
    if (tid == 0) {
        float M = fmaxf(fmaxf(lm[0], lm[1]), fmaxf(lm[2], lm[3]));
        float S = ls[0] * __expf(lm[0] - M) + ls[1] * __expf(lm[1] - M) +
                  ls[2] * __expf(lm[2] - M) + ls[3] * __expf(lm[3] - M);
        smp[b * 4 + q]       = M;
        smp[256 + b * 4 + q] = S;
    }
}

// ---- 7b) softmax finalize: y = exp(v - M) / S ------------------------------
__global__ __launch_bounds__(256) void k_smax2(const float* __restrict__ logits,
                                               const float* __restrict__ smp,
                                               float* __restrict__ y) {
    int q = blockIdx.x, b = blockIdx.y, tid = threadIdx.x;
    float m0 = smp[b * 4], m1 = smp[b * 4 + 1],
          m2 = smp[b * 4 + 2], m3 = smp[b * 4 + 3];
    float M = fmaxf(fmaxf(m0, m1), fmaxf(m2, m3));
    float S = smp[256 + b * 4]     * __expf(m0 - M) +
              smp[256 + b * 4 + 1] * __expf(m1 - M) +
              smp[256 + b * 4 + 2] * __expf(m2 - M) +
              smp[256 + b * 4 + 3] * __expf(m3 - M);
    float inv = 1.0f / S;
    const float4* row4 = (const float4*)(logits + (size_t)b * NV) + q * 2000;
    float4* y4 = (float4*)(y + (size_t)b * NV) + q * 2000;
    float4 v[8];
    #pragma unroll
    for (int j = 0; j < 8; ++j) {
        int idx = tid + 256 * j;
        v[j] = (idx < 2000) ? row4[idx] : make_float4(0.f, 0.f, 0.f, 0.f);
    }
    #pragma unroll
    for (int j = 0; j < 8; ++j) {
        int idx = tid + 256 * j;
        if (idx < 2000) {
            float4 o;
            o.x = __expf(v[j].x - M) * inv;
            o.y = __expf(v[j].y - M) * inv;
            o.z = __expf(v[j].z - M) * inv;
            o.w = __expf(v[j].w - M) * inv;
            y4[idx] = o;
        }
    }
}

extern "C" void kernel_launch(void* const* d_in, const int* in_sizes, int n_in,
                              void* d_out, int out_size, void* d_ws, size_t ws_size,
                              hipStream_t stream) {
    const int*   X   = (const int*)d_in[0];
    const float* a   = (const float*)d_in[1];
    const float* h   = (const float*)d_in[2];
    const float* c   = (const float*)d_in[3];
    const float* emb = (const float*)d_in[4];
    // d_in[5..10] = W1,b1,W2,b2,We,be — dead (softmax over size-1 axis == 1)
    const float* Wx  = (const float*)d_in[11];
    const float* Wh  = (const float*)d_in[12];
    const float* bl  = (const float*)d_in[13];
    const float* Wv  = (const float*)d_in[14];
    const float* bv  = (const float*)d_in[15];

    float* out = (float*)d_out;
    float* ws  = (float*)d_ws;
    float* At      = ws + OFF_AT;
    float* zacc    = ws + OFF_Z;
    float* Ht      = ws + OFF_HT;
    float* scratch = ws + OFF_SCR;   // part[] then (after it's dead) logits[]
    float* smp     = ws + OFF_SM;    // softmax partials (m[256], s[256])

    float* out_y     = out + OUT_Y;
    float* out_ctx   = out + OUT_CTX;
    float* out_alpha = out + OUT_ALPHA;
    float* out_h     = out + OUT_H;
    float* out_c     = out + OUT_C;

    hipLaunchKernelGGL(k_zinit,   dim3(1024),        dim3(256), 0, stream, bl, zacc);
    hipLaunchKernelGGL(k_ctx,     dim3(NTC, NB),     dim3(256), 0, stream, a, scratch);
    hipLaunchKernelGGL(k_ctx_fin, dim3(NB),          dim3(128), 0, stream, scratch, X, emb, h, At, out_ctx, out_alpha);
    hipLaunchKernelGGL(k_zgemm,   dim3(G4/128, ZKS), dim3(256), 0, stream, At, Wx, Wh, zacc);
    hipLaunchKernelGGL(k_gates,   dim3(NB),          dim3(256), 0, stream, zacc, c, out_h, out_c, Ht);
    hipLaunchKernelGGL(k_vgemm,   dim3(NV/128),      dim3(512), 0, stream, Ht, Wv, bv, scratch);
    hipLaunchKernelGGL(k_smax1,   dim3(4, NB),       dim3(256), 0, stream, scratch, smp);
    hipLaunchKernelGGL(k_smax2,   dim3(4, NB),       dim3(256), 0, stream, scratch, smp, out_y);
}

// Round 3
// 661.918 us; speedup vs baseline: 1.2842x; 1.0368x over previous
//
#include <hip/hip_runtime.h>
#include <hip/hip_bf16.h>
#include <math.h>

// Problem dims
constexpr int NB    = 64;
constexpr int NTX   = 1024;
constexpr int NAD   = 1024;   // ADIM
constexpr int NU    = 1024;   // UNITS
constexpr int NE    = 512;    // EDIM
constexpr int NV    = 32000;  // VOCAB
constexpr int KX    = NAD + NE;      // 1536 (rows of Wx)
constexpr int KTOT  = KX + NU;       // 2560 (concat K for z-GEMM)
constexpr int G4    = 4 * NU;        // 4096
constexpr int NTC   = 16;            // t-chunks for context reduce
constexpr int ZKS   = 16;            // z-GEMM k-split chunks (KTOT/ZKS = 160)

// Workspace layout (floats)
constexpr size_t OFF_AT  = 0;                          // At[k][b]  : KTOT*NB   = 163840
constexpr size_t OFF_Z   = OFF_AT + (size_t)KTOT * NB; // zacc[b][u]: NB*G4     = 262144
constexpr size_t OFF_HT  = OFF_Z + (size_t)NB * G4;    // Ht[k][b]  : NU*NB     = 65536
constexpr size_t OFF_SCR = OFF_HT + (size_t)NU * NB;   // union{ part[16][B][AD] , logits[B][V] }
constexpr size_t OFF_SM  = OFF_SCR + (size_t)NB * NV;  // softmax partials: 512 floats

// Out layout (fp32 elements), reference return order:
// (y_pred[B,V], context[B,1,A], alpha[B,Tx], h_new[B,U], c_new[B,U])
constexpr size_t OUT_Y     = 0;
constexpr size_t OUT_CTX   = (size_t)NB * NV;           // 2048000
constexpr size_t OUT_ALPHA = OUT_CTX + (size_t)NB * NAD;
constexpr size_t OUT_H     = OUT_ALPHA + (size_t)NB * NTX;
constexpr size_t OUT_C     = OUT_H + (size_t)NB * NU;

__device__ __forceinline__ float sigf(float x) { return 1.0f / (1.0f + __expf(-x)); }

// ---- 1) context partials + fused zacc:=bl init + fused alpha:=1 ------------
// grid (NTC, NB) x 256: 16*64*256 threads == NB*G4 exactly -> zinit fused.
// Block (tc,b): alpha[b][tc*64 .. tc*64+63] = 1.
__global__ __launch_bounds__(256) void k_ctx(const float* __restrict__ a,
                                             const float* __restrict__ bl,
                                             float* __restrict__ part,
                                             float* __restrict__ zacc,
                                             float* __restrict__ out_alpha) {
    int tc = blockIdx.x, b = blockIdx.y, tid = threadIdx.x;
    int gid = (tc * NB + b) * 256 + tid;
    zacc[gid] = bl[gid & (G4 - 1)];
    if (tid < 64) out_alpha[(size_t)b * NTX + tc * 64 + tid] = 1.0f;
    float4 acc = make_float4(0.f, 0.f, 0.f, 0.f);
    int t0 = tc * (NTX / NTC);
    #pragma unroll 8
    for (int tt = 0; tt < NTX / NTC; ++tt) {
        const float4* row = (const float4*)(a + ((size_t)b * NTX + t0 + tt) * NAD);
        float4 v = row[tid];                     // 4 f32, coalesced 16B/lane
        acc.x += v.x; acc.y += v.y; acc.z += v.z; acc.w += v.w;
    }
    float4* p4 = (float4*)(part + ((size_t)tc * NB + b) * NAD + tid * 4);
    *p4 = acc;
}

// ---- 2) finalize context; build At[k][b] = [ctx | emb | h] -----------------
__global__ __launch_bounds__(128) void k_ctx_fin(const float* __restrict__ part,
                                                 const int* __restrict__ X,
                                                 const float* __restrict__ emb,
                                                 const float* __restrict__ h,
                                                 float* __restrict__ At,
                                                 float* __restrict__ out_ctx) {
    int b = blockIdx.x, tid = threadIdx.x;
    int d0 = tid * 8;
    float s[8] = {};
    for (int tc = 0; tc < NTC; ++tc) {
        const float* p = part + ((size_t)tc * NB + b) * NAD + d0;
        #pragma unroll
        for (int i = 0; i < 8; ++i) s[i] += p[i];
    }
    #pragma unroll
    for (int i = 0; i < 8; ++i) {
        At[(size_t)(d0 + i) * NB + b] = s[i];
        out_ctx[(size_t)b * NAD + d0 + i] = s[i];
    }
    int row = X[b];
    for (int j = tid; j < NE; j += 128)
        At[(size_t)(NAD + j) * NB + b] = emb[(size_t)row * NE + j];
    for (int j = tid; j < NU; j += 128)
        At[(size_t)(KX + j) * NB + b] = h[(size_t)b * NU + j];
}

// ---- 3) z-GEMM: zacc[b][u] += sum_k At[k][b] * W[k][u] ---------------------
// float2 W loads + double-buffered pipeline; grid (G4/128, ZKS) = (32,16),
// 256 thr (4 waves x 16 b-rows). Chunk = 160 k = 20 groups of 8.
#define ZG_LD(buf, g)                                                          \
    _Pragma("unroll")                                                          \
    for (int j = 0; j < 8; ++j) {                                              \
        int k = kbeg + (g) * 8 + j;                                            \
        const float2* base = (k < KX) ? (Wx2 + (size_t)k * (G4 / 2))           \
                                      : (Wh2 + (size_t)(k - KX) * (G4 / 2));   \
        buf[j] = base[uq];                                                     \
    }

#define ZG_FMA(buf, g)                                                         \
    _Pragma("unroll")                                                          \
    for (int j = 0; j < 8; ++j) {                                              \
        const float* ap = At + (size_t)(kbeg + (g) * 8 + j) * NB + b0;         \
        _Pragma("unroll")                                                      \
        for (int i = 0; i < 16; ++i) {                                         \
            acc[i].x = fmaf(ap[i], buf[j].x, acc[i].x);                        \
            acc[i].y = fmaf(ap[i], buf[j].y, acc[i].y);                        \
        }                                                                      \
    }

__global__ __launch_bounds__(256) void k_zgemm(const float* __restrict__ At,
                                               const float* __restrict__ Wx,
                                               const float* __restrict__ Wh,
                                               float* __restrict__ zacc) {
    int tid = threadIdx.x;
    int lane = tid & 63;
    int b0 = __builtin_amdgcn_readfirstlane(tid >> 6) * 16;  // wave-uniform
    int uq = blockIdx.x * 64 + lane;                         // float2 index
    int kbeg = blockIdx.y * (KTOT / ZKS);                    // 160
    const float2* Wx2 = (const float2*)Wx;
    const float2* Wh2 = (const float2*)Wh;
    float2 acc[16];
    #pragma unroll
    for (int i = 0; i < 16; ++i) acc[i] = make_float2(0.f, 0.f);
    float2 bA[8], bB[8];
    constexpr int NG = (KTOT / ZKS) / 8;                     // 20 (even)
    ZG_LD(bA, 0);
    for (int g = 0; g < NG; g += 2) {
        ZG_LD(bB, g + 1);
        ZG_FMA(bA, g);
        if (g + 2 < NG) ZG_LD(bA, g + 2);
        ZG_FMA(bB, g + 1);
    }
    int u0 = uq * 2;
    #pragma unroll
    for (int i = 0; i < 16; ++i) {
        atomicAdd(&zacc[(size_t)(b0 + i) * G4 + u0],     acc[i].x);
        atomicAdd(&zacc[(size_t)(b0 + i) * G4 + u0 + 1], acc[i].y);
    }
}

// ---- 4) gates: c_new, h_new; Ht[k][b] for the vocab GEMM --------------------
__global__ __launch_bounds__(256) void k_gates(const float* __restrict__ zacc,
                                               const float* __restrict__ c,
                                               float* __restrict__ out_h,
                                               float* __restrict__ out_c,
                                               float* __restrict__ Ht) {
    int b = blockIdx.x, tid = threadIdx.x;
    const float* z = zacc + (size_t)b * G4;
    #pragma unroll
    for (int l = 0; l < 4; ++l) {
        int j = tid * 4 + l;
        float zi = z[j], zf = z[NU + j], zg = z[2 * NU + j], zo = z[3 * NU + j];
        float cf = c[(size_t)b * NU + j];
        float cn = sigf(zf) * cf + sigf(zi) * tanhf(zg);
        float hn = sigf(zo) * tanhf(cn);
        out_c[(size_t)b * NU + j] = cn;
        out_h[(size_t)b * NU + j] = hn;
        Ht[(size_t)j * NB + b] = hn;
    }
}

// ---- 5) vocab GEMM: logits[b][u] = sum_k Ht[k][b]*Wv[k][u] + bv[u] ----------
// Occupancy fix: grid NV/64 = 500 blocks x 512 thr (scalar f32 Wv columns,
// 64 cols/block) -> 4000 waves = 4 waves/SIMD (was 2). Same FLOPs/bytes,
// 2x the TLP to cover the ~900cy HBM latency of the strided Wv loads.
// 8 waves: (w&3) picks 16 b-rows, (w>>2) picks k-half; double-buffered
// 8-deep load groups; LDS reduce between k-halves; bias-folded store.
#define VG_LD(buf, g)                                                          \
    _Pragma("unroll")                                                          \
    for (int j = 0; j < 8; ++j)                                                \
        buf[j] = wp[(size_t)((g) * 8 + j) * NV];

#define VG_FMA(buf, g)                                                         \
    _Pragma("unroll")                                                          \
    for (int j = 0; j < 8; ++j) {                                              \
        const float* ap = Ht + (size_t)(kbeg + (g) * 8 + j) * NB + b0;         \
        _Pragma("unroll")                                                      \
        for (int i = 0; i < 16; ++i)                                           \
            acc[i] = fmaf(ap[i], buf[j], acc[i]);                              \
    }

__global__ __launch_bounds__(512) void k_vgemm(const float* __restrict__ Ht,
                                               const float* __restrict__ Wv,
                                               const float* __restrict__ bv,
                                               float* __restrict__ logits) {
    __shared__ float red[4][64][17];   // stride 17: odd -> conflict-free
    int tid = threadIdx.x;
    int lane = tid & 63;
    int w  = __builtin_amdgcn_readfirstlane(tid >> 6);
    int bw = w & 3;
    int kc = w >> 2;                   // 0 or 1: k-half
    int b0 = bw * 16;
    int u = blockIdx.x * 64 + lane;    // f32 column index
    int kbeg = kc * (NU / 2);          // 0 or 512
    const float* wp = Wv + (size_t)kbeg * NV + u;
    float acc[16] = {};
    float bA[8], bB[8];
    constexpr int NG = (NU / 2) / 8;   // 64 (even)
    VG_LD(bA, 0);
    for (int g = 0; g < NG; g += 2) {
        VG_LD(bB, g + 1);
        VG_FMA(bA, g);
        if (g + 2 < NG) VG_LD(bA, g + 2);
        VG_FMA(bB, g + 1);
    }
    if (kc == 1) {
        #pragma unroll
        for (int i = 0; i < 16; ++i)
            red[bw][lane][i] = acc[i];
    }
    __syncthreads();
    if (kc == 0) {
        float bvu = bv[u];
        #pragma unroll
        for (int i = 0; i < 16; ++i)
            logits[(size_t)(b0 + i) * NV + u] = acc[i] + red[bw][lane][i] + bvu;
    }
}

// ---- 6a) softmax partials: per (b, quarter) max & sum ----------------------
// grid (4, NB), 256 thr; each block scans 2000 float4 (8-deep batched loads).
__global__ __launch_bounds__(256) void k_smax1(const float* __restrict__ logits,
                                               float* __restrict__ smp) {
    __shared__ float lm[4], ls[4];
    int q = blockIdx.x, b = blockIdx.y, tid = threadIdx.x;
    const float4* row4 = (const float4*)(logits + (size_t)b * NV) + q * 2000;
    float4 v[8];
    #pragma unroll
    for (int j = 0; j < 8; ++j) {
        int idx = tid + 256 * j;
        v[j] = (idx < 2000) ? row4[idx]
                            : make_float4(-1e30f, -1e30f, -1e30f, -1e30f);
    }
    float m = -1e30f;
    #pragma unroll
    for (int j = 0; j < 8; ++j)
        m = fmaxf(m, fmaxf(fmaxf(v[j].x, v[j].y), fmaxf(v[j].z, v[j].w)));
    float s = 0.0f;
    #pragma unroll
    for (int j = 0; j < 8; ++j)
        s += __expf(v[j].x - m) + __expf(v[j].y - m) +
             __expf(v[j].z - m) + __expf(v[j].w - m);
    #pragma unroll
    for (int off = 32; off > 0; off >>= 1) {
        float om = __shfl_xor(m, off);
        float os = __shfl_xor(s, off);
        float M = fmaxf(m, om);
        s = s * __expf(m - M) + os * __expf(om - M);
        m = M;
    }
    int wv = tid >> 6, lane = tid & 63;
    if (lane == 0) { lm[wv] = m; ls[wv] = s; }
    __syncthreads();
    if (tid == 0) {
        float M = fmaxf(fmaxf(lm[0], lm[1]), fmaxf(lm[2], lm[3]));
        float S = ls[0] * __expf(lm[0] - M) + ls[1] * __expf(lm[1] - M) +
                  ls[2] * __expf(lm[2] - M) + ls[3] * __expf(lm[3] - M);
        smp[b * 4 + q]       = M;
        smp[256 + b * 4 + q] = S;
    }
}

// ---- 6b) softmax finalize: y = exp(v - M) / S ------------------------------
__global__ __launch_bounds__(256) void k_smax2(const float* __restrict__ logits,
                                               const float* __restrict__ smp,
                                               float* __restrict__ y) {
    int q = blockIdx.x, b = blockIdx.y, tid = threadIdx.x;
    float m0 = smp[b * 4], m1 = smp[b * 4 + 1],
          m2 = smp[b * 4 + 2], m3 = smp[b * 4 + 3];
    float M = fmaxf(fmaxf(m0, m1), fmaxf(m2, m3));
    float S = smp[256 + b * 4]     * __expf(m0 - M) +
              smp[256 + b * 4 + 1] * __expf(m1 - M) +
              smp[256 + b * 4 + 2] * __expf(m2 - M) +
              smp[256 + b * 4 + 3] * __expf(m3 - M);
    float inv = 1.0f / S;
    const float4* row4 = (const float4*)(logits + (size_t)b * NV) + q * 2000;
    float4* y4 = (float4*)(y + (size_t)b * NV) + q * 2000;
    float4 v[8];
    #pragma unroll
    for (int j = 0; j < 8; ++j) {
        int idx = tid + 256 * j;
        v[j] = (idx < 2000) ? row4[idx] : make_float4(0.f, 0.f, 0.f, 0.f);
    }
    #pragma unroll
    for (int j = 0; j < 8; ++j) {
        int idx = tid + 256 * j;
        if (idx < 2000) {
            float4 o;
            o.x = __expf(v[j].x - M) * inv;
            o.y = __expf(v[j].y - M) * inv;
            o.z = __expf(v[j].z - M) * inv;
            o.w = __expf(v[j].w - M) * inv;
            y4[idx] = o;
        }
    }
}

extern "C" void kernel_launch(void* const* d_in, const int* in_sizes, int n_in,
                              void* d_out, int out_size, void* d_ws, size_t ws_size,
                              hipStream_t stream) {
    const int*   X   = (const int*)d_in[0];
    const float* a   = (const float*)d_in[1];
    const float* h   = (const float*)d_in[2];
    const float* c   = (const float*)d_in[3];
    const float* emb = (const float*)d_in[4];
    // d_in[5..10] = W1,b1,W2,b2,We,be — dead (softmax over size-1 axis == 1)
    const float* Wx  = (const float*)d_in[11];
    const float* Wh  = (const float*)d_in[12];
    const float* bl  = (const float*)d_in[13];
    const float* Wv  = (const float*)d_in[14];
    const float* bv  = (const float*)d_in[15];

    float* out = (float*)d_out;
    float* ws  = (float*)d_ws;
    float* At      = ws + OFF_AT;
    float* zacc    = ws + OFF_Z;
    float* Ht      = ws + OFF_HT;
    float* scratch = ws + OFF_SCR;   // part[] then (after it's dead) logits[]
    float* smp     = ws + OFF_SM;    // softmax partials (m[256], s[256])

    float* out_y     = out + OUT_Y;
    float* out_ctx   = out + OUT_CTX;
    float* out_alpha = out + OUT_ALPHA;
    float* out_h     = out + OUT_H;
    float* out_c     = out + OUT_C;

    hipLaunchKernelGGL(k_ctx,     dim3(NTC, NB),     dim3(256), 0, stream, a, bl, scratch, zacc, out_alpha);
    hipLaunchKernelGGL(k_ctx_fin, dim3(NB),          dim3(128), 0, stream, scratch, X, emb, h, At, out_ctx);
    hipLaunchKernelGGL(k_zgemm,   dim3(G4/128, ZKS), dim3(256), 0, stream, At, Wx, Wh, zacc);
    hipLaunchKernelGGL(k_gates,   dim3(NB),          dim3(256), 0, stream, zacc, c, out_h, out_c, Ht);
    hipLaunchKernelGGL(k_vgemm,   dim3(NV/64),       dim3(512), 0, stream, Ht, Wv, bv, scratch);
    hipLaunchKernelGGL(k_smax1,   dim3(4, NB),       dim3(256), 0, stream, scratch, smp);
    hipLaunchKernelGGL(k_smax2,   dim3(4, NB),       dim3(256), 0, stream, scratch, smp, out_y);
}